// Round 1
// baseline (231.737 us; speedup 1.0000x reference)
//
#include <hip/hip_runtime.h>
#include <math.h>

#define T_BINS 350
#define REF_LEN 32
#define NB 32
#define NPIX 3072
#define N1 240
#define N2 10
#define NVAL 256

// ---------------------------------------------------------------------------
// Kernel 1 (fused): blocks 0..31 -> per-batch CSR build; blocks 32..223 ->
// 64x64 tiled transpose of w1; block 224 -> inverse bin map inv[t]=v or -1.
// (unchanged from previous round)
// ---------------------------------------------------------------------------
__global__ void prep(const int* __restrict__ inp,
                     int* __restrict__ pix,    // [NB][NPIX]
                     int* __restrict__ offs,   // [NB][NVAL]
                     int* __restrict__ cnts,   // [NB][NVAL]
                     const float* __restrict__ w1,
                     float* __restrict__ w1t,
                     const int* __restrict__ table,
                     int* __restrict__ inv)    // [T_BINS]
{
    __shared__ int lc[NVAL];
    __shared__ int ls[NVAL];
    __shared__ int lslot[NVAL];
    __shared__ float tile[64][65];
    __shared__ int linv[T_BINS];

    const int tid = threadIdx.x;

    if (blockIdx.x < NB) {
        // ---- CSR build for batch b ----
        const int b = blockIdx.x;
        lc[tid] = 0;
        __syncthreads();

        int vals[12];
        #pragma unroll
        for (int i = 0; i < 12; ++i) {
            int v = inp[b * NPIX + i * 256 + tid];   // coalesced
            vals[i] = v;
            atomicAdd(&lc[v], 1);
        }
        __syncthreads();

        int x = lc[tid];
        ls[tid] = x;
        __syncthreads();
        for (int d = 1; d < 256; d <<= 1) {
            int y = (tid >= d) ? ls[tid - d] : 0;
            __syncthreads();
            ls[tid] += y;
            __syncthreads();
        }
        int excl = ls[tid] - x;
        offs[b * NVAL + tid] = excl;
        cnts[b * NVAL + tid] = x;
        lslot[tid] = excl;
        __syncthreads();

        #pragma unroll
        for (int i = 0; i < 12; ++i) {
            int slot = atomicAdd(&lslot[vals[i]], 1);
            pix[b * NPIX + slot] = i * 256 + tid;
        }
    } else if (blockIdx.x < NB + 192) {
        // ---- transpose tile ----
        const int tt = blockIdx.x - NB;       // 0..191
        const int p0 = (tt % 48) * 64;
        const int n0 = (tt / 48) * 64;
        const int c  = tid & 63;
        const int r0 = tid >> 6;              // 0..3

        #pragma unroll
        for (int i = 0; i < 16; ++i) {
            int n = n0 + r0 + i * 4;
            if (n < N1) tile[r0 + i * 4][c] = w1[n * NPIX + p0 + c];
        }
        __syncthreads();
        #pragma unroll
        for (int i = 0; i < 16; ++i) {
            int p = p0 + r0 + i * 4;
            int n = n0 + c;
            if (n < N1) w1t[p * N1 + n] = tile[c][r0 + i * 4];
        }
    } else {
        // ---- inverse bin map (table is injective value->bin) ----
        for (int i = tid; i < T_BINS; i += 256) linv[i] = -1;
        __syncthreads();
        if (tid < NVAL) linv[table[tid]] = tid;
        __syncthreads();
        for (int i = tid; i < T_BINS; i += 256) inv[i] = linv[i];
    }
}

// ---------------------------------------------------------------------------
// Kernel 2: W[b][v][n] = sum over pixels with value v of w1t[p, n].
// Same per-element math as the previous u1t kernel (ascending-order fp64
// accumulate, single fp32 rounding), but indexed by value v instead of
// time bin t: skips the 94 empty bins entirely (7.86 MB vs 10.75 MB) and
// runs 4 values per block (2048 blocks vs 11200).
// ---------------------------------------------------------------------------
__global__ void compute_w(const float* __restrict__ w1t,
                          const int* __restrict__ pix,
                          const int* __restrict__ offs,
                          const int* __restrict__ cnts,
                          float* __restrict__ W)     // [NB][NVAL][N1]
{
    const int b   = blockIdx.y;
    const int tid = threadIdx.x;
    if (tid >= N1) return;

    for (int vv = 0; vv < 4; ++vv) {
        const int v = blockIdx.x * 4 + vv;
        const int cnt = cnts[b * NVAL + v];
        const int* pl = pix + b * NPIX + offs[b * NVAL + v];
        double acc = 0.0;
        int i = 0;
        for (; i + 4 <= cnt; i += 4) {
            int p0 = pl[i], p1 = pl[i + 1], p2 = pl[i + 2], p3 = pl[i + 3];
            double w0  = (double)w1t[p0 * N1 + tid];
            double w1v = (double)w1t[p1 * N1 + tid];
            double w2v = (double)w1t[p2 * N1 + tid];
            double w3  = (double)w1t[p3 * N1 + tid];
            acc += w0; acc += w1v; acc += w2v; acc += w3;   // ascending order
        }
        for (; i < cnt; ++i)
            acc += (double)w1t[pl[i] * N1 + tid];
        W[((size_t)b * NVAL + v) * N1 + tid] = (float)acc;
    }
}

// ---------------------------------------------------------------------------
// Dynamics math (identical constants/ops to previous round):
//   PSP alpha-kernel exact IIR:  q=A(q+p); p=Ap+u; y=(e/10)q   A=e^-0.1
//   Truncated 32-tap refractory exact IIR with expiry corrections from
//   bits 30/31 of the spike-history mask.
// ---------------------------------------------------------------------------
#define DYN_CONSTS \
    const double A    = 0.9048374180359595;     \
    const double C    = 0.2718281828459045;     \
    const double Ar   = 0.36787944117144233;    \
    const double Cr   = -54.365636569180904;    \
    const double C31A = 1.0671679036256927e-12; \
    const double C31B = 3.4424771084699765e-14;

#define DYN_CORE(uin)                                         \
        q = A * (q + p);                                      \
        p = A * p + (uin);                                    \
        double vm = C * q + Cr * Q;                           \
        unsigned int sb = (vm >= 10.0) ? 1u : 0u;             \
        double s = (double)sb;                                \
        double sel31 = (hist & 0x80000000u) ? C31A : 0.0;     \
        double sel30 = (hist & 0x40000000u) ? C31B : 0.0;     \
        Q = Ar * (Q + P - sel31);                             \
        P = s + (Ar * P - sel30);                             \
        hist = (hist << 1) | sb;

// ---------------------------------------------------------------------------
// Kernel 3 (fused): one block per batch (256 threads = 4 waves).
//   phase 1: layer-1 dynamics, wave k owns neurons k*64.., reads W via
//            inv[t] (monotone -> streaming), ballot masks -> LDS.
//   phase 2: u2[t][m] = bit-walk of masks x LDS w2 -> LDS (identical bit
//            order to the previous compute_u2).
//   phase 3: layer-2 IIR on 10 lanes, 14-deep LDS prefetch, spikes written
//            back in place.
//   phase 4: coalesced store of out[b][m][t].
// Removes s1m/u2 global round-trips, 2 kernel launches, and the previous
// layer2 kernel's 64-way-scattered stores.
// ---------------------------------------------------------------------------
__global__ __launch_bounds__(256) void fused_dyn(
        const float* __restrict__ W,     // [NB][NVAL][N1]
        const int* __restrict__ inv,     // [T_BINS]
        const float* __restrict__ w2,    // [N2][N1]
        float* __restrict__ out)         // [NB][N2][T_BINS]
{
    __shared__ unsigned long long smask[T_BINS][4];   // 11.2 KB
    __shared__ float lw2[N2][N1];                     // 9.6 KB
    __shared__ float su2[T_BINS][N2];                 // 14 KB
    __shared__ int linv[T_BINS];                      // 1.4 KB

    const int tid  = threadIdx.x;
    const int b    = blockIdx.x;
    const int k    = tid >> 6;        // wave 0..3
    const int lane = tid & 63;
    const int n    = k * 64 + lane;   // neuron id; >=N1 for wave3 lanes 48..63

    for (int i = tid; i < N2 * N1; i += 256) lw2[i / N1][i % N1] = w2[i];
    for (int i = tid; i < T_BINS; i += 256) linv[i] = inv[i];
    __syncthreads();

    // ---- phase 1: layer-1 dynamics ----
    {
        DYN_CONSTS
        double p = 0.0, q = 0.0, P = 0.0, Q = 0.0;
        unsigned int hist = 0u;
        const bool valid = (n < N1);
        const float* Wb = W + (size_t)b * NVAL * N1 + (valid ? n : 0);

        double cb[14], nb[14];
        #pragma unroll
        for (int i = 0; i < 14; ++i) {
            int v = linv[i];
            cb[i] = (valid && v >= 0) ? (double)Wb[(size_t)v * N1] : 0.0;
        }

        for (int t0 = 0; t0 < T_BINS; t0 += 14) {
            if (t0 + 14 < T_BINS) {
                #pragma unroll
                for (int i = 0; i < 14; ++i) {
                    int v = linv[t0 + 14 + i];
                    nb[i] = (valid && v >= 0) ? (double)Wb[(size_t)v * N1] : 0.0;
                }
            }
            #pragma unroll
            for (int i = 0; i < 14; ++i) {
                DYN_CORE(cb[i])
                unsigned long long msk = __ballot(sb != 0u);
                if (lane == 0) smask[t0 + i][k] = msk;
            }
            #pragma unroll
            for (int i = 0; i < 14; ++i) cb[i] = nb[i];
        }
    }
    __syncthreads();

    // ---- phase 2: u2 = masks · w2 (same bit order as before: kk asc, ffs asc)
    for (int id = tid; id < T_BINS * N2; id += 256) {
        const int t = id / N2;
        const int m = id - t * N2;
        double acc = 0.0;
        #pragma unroll
        for (int kk = 0; kk < 4; ++kk) {
            unsigned long long msk = smask[t][kk];
            while (msk) {
                int j = __ffsll(msk) - 1;
                acc += (double)lw2[m][kk * 64 + j];
                msk &= msk - 1;
            }
        }
        su2[t][m] = (float)acc;
    }
    __syncthreads();

    // ---- phase 3: layer-2 dynamics on 10 lanes, spikes written in place ----
    if (tid < N2) {
        const int m = tid;
        DYN_CONSTS
        double p = 0.0, q = 0.0, P = 0.0, Q = 0.0;
        unsigned int hist = 0u;

        double cb[14], nb[14];
        #pragma unroll
        for (int i = 0; i < 14; ++i) cb[i] = (double)su2[i][m];

        for (int t0 = 0; t0 < T_BINS; t0 += 14) {
            if (t0 + 14 < T_BINS) {
                #pragma unroll
                for (int i = 0; i < 14; ++i) nb[i] = (double)su2[t0 + 14 + i][m];
            }
            #pragma unroll
            for (int i = 0; i < 14; ++i) {
                DYN_CORE(cb[i])
                su2[t0 + i][m] = (float)s;   // overwrite u2 with spike
            }
            #pragma unroll
            for (int i = 0; i < 14; ++i) cb[i] = nb[i];
        }
    }
    __syncthreads();

    // ---- phase 4: coalesced output out[b][m][t] ----
    float* ob = out + (size_t)b * N2 * T_BINS;
    for (int id = tid; id < N2 * T_BINS; id += 256) {
        const int m = id / T_BINS;
        const int t = id - m * T_BINS;
        ob[id] = su2[t][m];
    }
}

// ---------------------------------------------------------------------------
extern "C" void kernel_launch(void* const* d_in, const int* in_sizes, int n_in,
                              void* d_out, int out_size, void* d_ws, size_t ws_size,
                              hipStream_t stream) {
    const int*   inp   = (const int*)d_in[0];    // [32,3,32,32]
    const int*   table = (const int*)d_in[1];    // [256]
    const float* w1    = (const float*)d_in[2];  // [240,3072]
    const float* w2    = (const float*)d_in[3];  // [10,240]
    float* out = (float*)d_out;                  // [32,10,350]

    char* ws = (char*)d_ws;
    size_t off = 0;
    float* W   = (float*)(ws + off);  off += (size_t)NB * NVAL * N1 * 4;     // 7.86 MB
    float* w1t = (float*)(ws + off);  off += (size_t)NPIX * N1 * 4;          // 2.9 MB
    int*   pix = (int*)(ws + off);    off += (size_t)NB * NPIX * 4;
    int*  offs = (int*)(ws + off);    off += (size_t)NB * NVAL * 4;
    int*  cnts = (int*)(ws + off);    off += (size_t)NB * NVAL * 4;
    int*   inv = (int*)(ws + off);    off += (size_t)T_BINS * 4;

    prep<<<NB + 192 + 1, 256, 0, stream>>>(inp, pix, offs, cnts, w1, w1t, table, inv);
    compute_w<<<dim3(NVAL / 4, NB), 256, 0, stream>>>(w1t, pix, offs, cnts, W);
    fused_dyn<<<NB, 256, 0, stream>>>(W, inv, w2, out);
}